// Round 6
// baseline (133.104 us; speedup 1.0000x reference)
//
#include <hip/hip_runtime.h>

#define N_NODES 50000
#define N_EDGES 640000
#define CH 128
#define NBINS 1563    // bins of 32 rows (row >> 5); one bin per fused block
#define NTILES 1563   // gather tiles of 32 rows == NBINS
#define BINB 256      // binning blocks
#define EPB 2500      // edges per binning block (256*2500 = 640000)
#define CAPR 48       // per-row LDS slot capacity; P(deg>48) ~ 1e-15

typedef __bf16 bf16_t;
typedef bf16_t bf16x8 __attribute__((ext_vector_type(8)));
typedef float f32x4 __attribute__((ext_vector_type(4)));

__device__ __forceinline__ ushort f2bf(float f) {
  union { float f; unsigned u; } v; v.f = f;
  unsigned r = v.u + 0x7FFFu + ((v.u >> 16) & 1u);   // RNE
  return (ushort)(r >> 16);
}
__device__ __forceinline__ float bflo(unsigned u) {
  union { unsigned u; float f; } v; v.u = u << 16; return v.f;
}
__device__ __forceinline__ float bfhi(unsigned u) {
  union { unsigned u; float f; } v; v.u = u & 0xFFFF0000u; return v.f;
}
__device__ __forceinline__ unsigned pack2(float lo, float hi) {
  return (unsigned)f2bf(lo) | ((unsigned)f2bf(hi) << 16);
}
__device__ __forceinline__ void addrow(float* acc, uint4 v) {
  acc[0] += bflo(v.x); acc[1] += bfhi(v.x);
  acc[2] += bflo(v.y); acc[3] += bfhi(v.y);
  acc[4] += bflo(v.z); acc[5] += bfhi(v.z);
  acc[6] += bflo(v.w); acc[7] += bfhi(v.w);
}

// ws layout (bytes), 16B-aligned:
//   binRec : [0, 2560000)           640000 uint, block i's records DENSE at
//            [i*EPB, (i+1)*EPB), grouped by bin. rec = (lrow5 << 16) | col16.
//   obot   : [2560000, 3360768)     TRANSPOSED offsets: obot[g*BINB + i] =
//            offset of bin g inside block i's region; row NBINS = sentinel EPB.
//            Fused block g reads 2 contiguous 512-B rows (fully coalesced).
//   Wb     : [3360768, 3393536)     128x128 bf16
//   xb     : [3393536, 16193536)    N_NODES*CH bf16
// Binning is LDS-local (histogram/scan/place): zero global atomics, all
// row/col staged in registers once, coalesced record dump.

// Binning only: 256 blocks x 2500 edges. Separate kernel so its 17.5 KB LDS
// isn't charged to the conversion blocks, and so rocprof reports it alone.
__global__ __launch_bounds__(256) void bink(const int* __restrict__ row,
                                            const int* __restrict__ col,
                                            unsigned* __restrict__ binRec,
                                            ushort* __restrict__ obot) {
  __shared__ int cnt[NBINS];                      // 6252 B: hist, then offsets
  __shared__ int parts[256];
  __shared__ __align__(16) unsigned recbuf[EPB];  // 10000 B
  int bid = blockIdx.x;
  int tid = threadIdx.x;
  for (int i = tid; i < NBINS; i += 256) cnt[i] = 0;
  __syncthreads();
  int base = bid * EPB;
  // stage all edge data into registers: 6 independent int4 loads in flight
  int4 r4s[3], c4s[3];
  bool val[3];
#pragma unroll
  for (int b = 0; b < 3; ++b) {
    int idx4 = b * 1024 + tid * 4;
    val[b] = idx4 < EPB;                          // EPB%4==0: all-or-nothing
    if (val[b]) {
      r4s[b] = *(const int4*)(row + base + idx4);
      c4s[b] = *(const int4*)(col + base + idx4);
    }
  }
  // pass 1: LDS histogram + per-record rank; keep (bi,lrow5,rk) + col in regs
  unsigned pkv[12];                               // (bi<<13)|(lrow5<<8)|rk
  unsigned colp[6];                               // cols packed 2 per reg
#pragma unroll
  for (int b = 0; b < 3; ++b) {
    if (val[b]) {
      int rr[4] = {r4s[b].x, r4s[b].y, r4s[b].z, r4s[b].w};
      int cc[4] = {c4s[b].x, c4s[b].y, c4s[b].z, c4s[b].w};
#pragma unroll
      for (int j = 0; j < 4; ++j) {
        int bi = rr[j] >> 5;
        int rk = atomicAdd(&cnt[bi], 1);          // LDS atomic: cheap
        pkv[b * 4 + j] = ((unsigned)bi << 13) |
                         ((unsigned)(rr[j] & 31) << 8) | (unsigned)rk;
      }
      colp[b * 2]     = ((unsigned)cc[0] & 0xFFFFu) | ((unsigned)cc[1] << 16);
      colp[b * 2 + 1] = ((unsigned)cc[2] & 0xFFFFu) | ((unsigned)cc[3] << 16);
    } else {
#pragma unroll
      for (int j = 0; j < 4; ++j) pkv[b * 4 + j] = 0xFFFFFFFFu;
      colp[b * 2] = 0; colp[b * 2 + 1] = 0;
    }
  }
  __syncthreads();
  // in-block exclusive scan of cnt (chunks of 7, 256*7 >= NBINS)
  int c7[7];
  int s = 0;
#pragma unroll
  for (int k = 0; k < 7; ++k) {
    int i = tid * 7 + k;
    int c = (i < NBINS) ? cnt[i] : 0;
    c7[k] = c; s += c;
  }
  parts[tid] = s;
  __syncthreads();
  for (int off = 1; off < 256; off <<= 1) {       // Hillis-Steele inclusive
    int v = (tid >= off) ? parts[tid - off] : 0;
    __syncthreads();
    parts[tid] += v;
    __syncthreads();
  }
  int run = (tid > 0) ? parts[tid - 1] : 0;
#pragma unroll
  for (int k = 0; k < 7; ++k) {
    int i = tid * 7 + k;
    if (i < NBINS) {
      obot[i * BINB + bid] = (ushort)run;         // transposed offset table
      cnt[i] = run;                               // cnt becomes offset
      run += c7[k];
    }
  }
  if (tid == 0) obot[NBINS * BINB + bid] = (ushort)EPB;
  __syncthreads();
  // pass 2: pure register -> LDS placement (no global reloads)
#pragma unroll
  for (int k = 0; k < 12; ++k) {
    unsigned p = pkv[k];
    if (p != 0xFFFFFFFFu) {
      int bi = (int)(p >> 13);
      int lr5 = (int)((p >> 8) & 31u);
      int rk = (int)(p & 255u);
      unsigned cw = (colp[k >> 1] >> ((k & 1) * 16)) & 0xFFFFu;
      recbuf[cnt[bi] + rk] = ((unsigned)lr5 << 16) | cw;
    }
  }
  __syncthreads();
  // coalesced dump: 625 uint4
  uint4* gb4 = (uint4*)(binRec + base);
  const uint4* rb4 = (const uint4*)recbuf;
  for (int j = tid; j < EPB / 4; j += 256) gb4[j] = rb4[j];
}

// Conversion only: no LDS -> full occupancy, pure BW.
// Blocks [0,3125): x -> bf16. Block 3125: W -> bf16.
__global__ __launch_bounds__(256) void conv(const float4* __restrict__ x4,
                                            uint4* __restrict__ xb4,
                                            const float4* __restrict__ W4,
                                            uint4* __restrict__ Wb4) {
  int bid = blockIdx.x;
  int tid = threadIdx.x;
  if (bid < 3125) {
    int i = bid * 256 + tid;                      // 800000 threads exactly
    float4 a = x4[i * 2], b = x4[i * 2 + 1];
    uint4 o;
    o.x = pack2(a.x, a.y); o.y = pack2(a.z, a.w);
    o.z = pack2(b.x, b.y); o.w = pack2(b.z, b.w);
    xb4[i] = o;
  } else {
    for (int i = tid; i < 2048; i += 256) {
      float4 c = W4[i * 2], d = W4[i * 2 + 1];
      uint4 w;
      w.x = pack2(c.x, c.y); w.y = pack2(c.z, c.w);
      w.z = pack2(d.x, d.y); w.w = pack2(d.z, d.w);
      Wb4[i] = w;
    }
  }
}

// Fused Stage A (256 dense runs, coalesced transposed offsets) + Stage B
// (gather+normalize+residual, 512 threads, ONE row per 16-lane group, 8-wide
// unrolled) + GEMM (swapped-operand MFMA, hT XOR-swizzled, 8 waves x 2
// n-tiles). One 32-row tile per block.
__global__ __launch_bounds__(512) void fused(const uint4* __restrict__ xb4,
                                             const unsigned* __restrict__ binRec,
                                             const ushort* __restrict__ obot,
                                             const uint4* __restrict__ Wb4,
                                             const float4* __restrict__ bias4,
                                             float4* __restrict__ out4) {
  __shared__ ushort hT[32 * CH];                   // 8192 B, slot s at s^(r&15)
  __shared__ __align__(16) ushort colL[32 * CAPR]; // 3072 B
  __shared__ int rowcnt[32];
  int tid = threadIdx.x;
  int g = blockIdx.x;
  int m0 = g * 32;

  // ---- Stage A: 256 dense runs, 2 threads per run; offsets coalesced ----
  if (tid < 32) rowcnt[tid] = 0;
  __syncthreads();
  {
    int i = tid >> 1, sub = tid & 1;
    int o0 = obot[g * BINB + i];                   // contiguous 512-B row
    int o1 = obot[(g + 1) * BINB + i];             // contiguous 512-B row
    const unsigned* rbase = binRec + i * EPB;
    for (int p = o0 + sub; p < o1; p += 2) {
      unsigned rec = rbase[p];
      int lr = (int)(rec >> 16);
      int pp = atomicAdd(&rowcnt[lr], 1);
      if (pp < CAPR) colL[lr * CAPR + pp] = (ushort)(rec & 0xFFFFu);
    }
  }
  __syncthreads();

  // ---- Stage B: gather + normalize + residual -> hT (bf16), single pass ----
  int wv = tid >> 6;          // 0..7
  int lane = tid & 63;
  int q = lane & 15;          // uint4 chunk within a 128-ch bf16 row
  int grp = lane >> 4;        // 0..3
  int r = wv * 4 + grp;       // 0..31
  int node = m0 + r;
  int deg = rowcnt[r];
  int degc = deg < CAPR ? deg : CAPR;
  const ushort* arow = colL + r * CAPR;
  int nc = node < N_NODES ? node : 0;
  uint4 xi = xb4[nc * 16 + q];           // residual, issued before the loop
  float acc[8] = {0.f, 0.f, 0.f, 0.f, 0.f, 0.f, 0.f, 0.f};
  int e = 0;
  for (; e + 7 < degc; e += 8) {         // 8 independent loads in flight
    uint4 ids = *(const uint4*)(arow + e);
    int n0 = ids.x & 0xFFFF, n1 = ids.x >> 16;
    int n2 = ids.y & 0xFFFF, n3 = ids.y >> 16;
    int n4 = ids.z & 0xFFFF, n5 = ids.z >> 16;
    int n6 = ids.w & 0xFFFF, n7 = ids.w >> 16;
    uint4 v0 = xb4[n0 * 16 + q];
    uint4 v1 = xb4[n1 * 16 + q];
    uint4 v2 = xb4[n2 * 16 + q];
    uint4 v3 = xb4[n3 * 16 + q];
    uint4 v4 = xb4[n4 * 16 + q];
    uint4 v5 = xb4[n5 * 16 + q];
    uint4 v6 = xb4[n6 * 16 + q];
    uint4 v7 = xb4[n7 * 16 + q];
    addrow(acc, v0); addrow(acc, v1); addrow(acc, v2); addrow(acc, v3);
    addrow(acc, v4); addrow(acc, v5); addrow(acc, v6); addrow(acc, v7);
  }
  if (e + 3 < degc) {
    uint2 ids = *(const uint2*)(arow + e);
    int n0 = ids.x & 0xFFFF, n1 = ids.x >> 16;
    int n2 = ids.y & 0xFFFF, n3 = ids.y >> 16;
    uint4 v0 = xb4[n0 * 16 + q];
    uint4 v1 = xb4[n1 * 16 + q];
    uint4 v2 = xb4[n2 * 16 + q];
    uint4 v3 = xb4[n3 * 16 + q];
    addrow(acc, v0); addrow(acc, v1); addrow(acc, v2); addrow(acc, v3);
    e += 4;
  }
  for (; e < degc; ++e) {
    uint4 v = xb4[(int)arow[e] * 16 + q];
    addrow(acc, v);
  }
  uint4 o = make_uint4(0, 0, 0, 0);
  if (node < N_NODES) {
    float s = 1.0f / fmaxf((float)deg, 1.0f);
    o.x = pack2(bflo(xi.x) + acc[0] * s, bfhi(xi.x) + acc[1] * s);
    o.y = pack2(bflo(xi.y) + acc[2] * s, bfhi(xi.y) + acc[3] * s);
    o.z = pack2(bflo(xi.z) + acc[4] * s, bfhi(xi.z) + acc[5] * s);
    o.w = pack2(bflo(xi.w) + acc[6] * s, bfhi(xi.w) + acc[7] * s);
  }
  *(uint4*)&hT[r * CH + ((q ^ (r & 15)) << 3)] = o;
  __syncthreads();

  // ---- GEMM: swapped-operand MFMA (proven mapping), 8 waves x 2 n-tiles.
  // hT uint4-slot s of row r lives at s^(r&15): conflict-free fragment reads.
  int qq = grp;
  int mt = wv & 1;
  int nbase = (wv >> 1) * 2;
  const ushort* hbase = &hT[(mt * 16 + q) * CH];   // row rr_: rr_&15 == q
  bf16x8 hb0 = *(const bf16x8*)(hbase + (((qq + 0) ^ q) << 3));
  bf16x8 hb1 = *(const bf16x8*)(hbase + (((qq + 4) ^ q) << 3));
  bf16x8 hb2 = *(const bf16x8*)(hbase + (((qq + 8) ^ q) << 3));
  bf16x8 hb3 = *(const bf16x8*)(hbase + (((qq + 12) ^ q) << 3));
  int m = m0 + mt * 16 + q;
#pragma unroll
  for (int i = 0; i < 2; ++i) {
    int nt = nbase + i;
    const uint4* wr = Wb4 + (nt * 16 + q) * 16 + qq;   // k-step 32 bf16 = 4 uint4
    bf16x8 w0 = __builtin_bit_cast(bf16x8, wr[0]);
    bf16x8 w1 = __builtin_bit_cast(bf16x8, wr[4]);
    bf16x8 w2 = __builtin_bit_cast(bf16x8, wr[8]);
    bf16x8 w3 = __builtin_bit_cast(bf16x8, wr[12]);
    f32x4 acc2 = {0.f, 0.f, 0.f, 0.f};
    acc2 = __builtin_amdgcn_mfma_f32_16x16x32_bf16(w0, hb0, acc2, 0, 0, 0);
    acc2 = __builtin_amdgcn_mfma_f32_16x16x32_bf16(w1, hb1, acc2, 0, 0, 0);
    acc2 = __builtin_amdgcn_mfma_f32_16x16x32_bf16(w2, hb2, acc2, 0, 0, 0);
    acc2 = __builtin_amdgcn_mfma_f32_16x16x32_bf16(w3, hb3, acc2, 0, 0, 0);
    if (m < N_NODES) {
      float4 bv = bias4[nt * 4 + qq];
      f32x4 ov;
      ov.x = acc2[0] + bv.x;
      ov.y = acc2[1] + bv.y;
      ov.z = acc2[2] + bv.z;
      ov.w = acc2[3] + bv.w;
      __builtin_nontemporal_store(ov, (f32x4*)(out4 + (size_t)m * 32 + nt * 4 + qq));
    }
  }
}

extern "C" void kernel_launch(void* const* d_in, const int* in_sizes, int n_in,
                              void* d_out, int out_size, void* d_ws, size_t ws_size,
                              hipStream_t stream) {
  const float* x  = (const float*)d_in[0];
  const int*   ei = (const int*)d_in[1];    // [2, N_EDGES]: row then col
  const float* W  = (const float*)d_in[2];
  const float* bb = (const float*)d_in[3];

  char* ws = (char*)d_ws;
  unsigned* binRec = (unsigned*)ws;
  ushort*   obot   = (ushort*)(ws + 2560000);
  uint4*    Wb4    = (uint4*)(ws + 3360768);
  uint4*    xb4    = (uint4*)(ws + 3393536);

  bink<<<BINB, 256, 0, stream>>>(ei, ei + N_EDGES, binRec, obot);
  conv<<<3126, 256, 0, stream>>>((const float4*)x, xb4, (const float4*)W, Wb4);
  fused<<<NTILES, 512, 0, stream>>>(xb4, binRec, obot, Wb4,
                                    (const float4*)bb, (float4*)d_out);
}

// Round 8
// 129.609 us; speedup vs baseline: 1.0270x; 1.0270x over previous
//
#include <hip/hip_runtime.h>

#define N_NODES 50000
#define N_EDGES 640000
#define CH 128
#define NBINS 1563    // bins of 32 rows (row >> 5); one bin per fused block
#define NTILES 1563   // gather tiles of 32 rows == NBINS
#define BINB 256      // binning blocks
#define EPB 2500      // edges per binning block (256*2500 = 640000)
#define CAPR 48       // per-row LDS slot capacity; P(deg>48) ~ 1e-15
#define ZID N_NODES   // zero-row sentinel id (xb row of zeros)

typedef __bf16 bf16_t;
typedef bf16_t bf16x8 __attribute__((ext_vector_type(8)));
typedef float f32x4 __attribute__((ext_vector_type(4)));

__device__ __forceinline__ ushort f2bf(float f) {
  union { float f; unsigned u; } v; v.f = f;
  unsigned r = v.u + 0x7FFFu + ((v.u >> 16) & 1u);   // RNE
  return (ushort)(r >> 16);
}
__device__ __forceinline__ float bflo(unsigned u) {
  union { unsigned u; float f; } v; v.u = u << 16; return v.f;
}
__device__ __forceinline__ float bfhi(unsigned u) {
  union { unsigned u; float f; } v; v.u = u & 0xFFFF0000u; return v.f;
}
__device__ __forceinline__ unsigned pack2(float lo, float hi) {
  return (unsigned)f2bf(lo) | ((unsigned)f2bf(hi) << 16);
}
__device__ __forceinline__ void addrow(float* acc, uint4 v) {
  acc[0] += bflo(v.x); acc[1] += bfhi(v.x);
  acc[2] += bflo(v.y); acc[3] += bfhi(v.y);
  acc[4] += bflo(v.z); acc[5] += bfhi(v.z);
  acc[6] += bflo(v.w); acc[7] += bfhi(v.w);
}

// ws layout (bytes), 16B-aligned:
//   binRec : [0, 2560000)           640000 uint, block i's records DENSE at
//            [i*EPB, (i+1)*EPB), grouped by bin. rec = (lrow5 << 16) | col16.
//   obot   : [2560000, 3360768)     TRANSPOSED offsets: obot[g*BINB + i] =
//            offset of bin g inside block i's region; row NBINS = sentinel EPB.
//   Wb     : [3360768, 3393536)     128x128 bf16
//   xb     : [3393536, 16193792)    (N_NODES+1)*CH bf16; row N_NODES = zeros
//            (gather-pad sentinel: loads of it are L1-resident, add 0.0).
// Binning is LDS-local (histogram/scan/place): zero global atomics, all
// row/col staged in registers once, coalesced record dump.

// Merged prep: blocks [0,256) LDS-binning (2500 edges each); blocks
// [256,3381) x -> bf16 (NT reads, cached writes); block 3381: W + zero row.
// Merge rationale: bink's 256 latency-bound blocks co-run with conv's
// BW-bound blocks (machine-level overlap), 2 fewer launch gaps. 17.5 KB LDS
// still allows 8 conv-blocks/CU (round-4's 46 KB capped at 3 -> regressed).
__global__ __launch_bounds__(256) void prep(const int* __restrict__ row,
                                            const int* __restrict__ col,
                                            unsigned* __restrict__ binRec,
                                            ushort* __restrict__ obot,
                                            const f32x4* __restrict__ x4,
                                            uint4* __restrict__ xb4,
                                            const float4* __restrict__ W4,
                                            uint4* __restrict__ Wb4) {
  __shared__ int cnt[NBINS];                      // 6252 B: hist, then offsets
  __shared__ int parts[256];
  __shared__ __align__(16) unsigned recbuf[EPB];  // 10000 B
  int bid = blockIdx.x;
  int tid = threadIdx.x;
  if (bid < BINB) {
    for (int i = tid; i < NBINS; i += 256) cnt[i] = 0;
    __syncthreads();
    int base = bid * EPB;
    // stage all edge data into registers: 6 independent int4 loads in flight
    int4 r4s[3], c4s[3];
    bool val[3];
#pragma unroll
    for (int b = 0; b < 3; ++b) {
      int idx4 = b * 1024 + tid * 4;
      val[b] = idx4 < EPB;                        // EPB%4==0: all-or-nothing
      if (val[b]) {
        r4s[b] = *(const int4*)(row + base + idx4);
        c4s[b] = *(const int4*)(col + base + idx4);
      }
    }
    // pass 1: LDS histogram + per-record rank; keep (bi,lrow5,rk)+col in regs
    unsigned pkv[12];                             // (bi<<13)|(lrow5<<8)|rk
    unsigned colp[6];                             // cols packed 2 per reg
#pragma unroll
    for (int b = 0; b < 3; ++b) {
      if (val[b]) {
        int rr[4] = {r4s[b].x, r4s[b].y, r4s[b].z, r4s[b].w};
        int cc[4] = {c4s[b].x, c4s[b].y, c4s[b].z, c4s[b].w};
#pragma unroll
        for (int j = 0; j < 4; ++j) {
          int bi = rr[j] >> 5;
          int rk = atomicAdd(&cnt[bi], 1);        // LDS atomic: cheap
          pkv[b * 4 + j] = ((unsigned)bi << 13) |
                           ((unsigned)(rr[j] & 31) << 8) | (unsigned)rk;
        }
        colp[b * 2]     = ((unsigned)cc[0] & 0xFFFFu) | ((unsigned)cc[1] << 16);
        colp[b * 2 + 1] = ((unsigned)cc[2] & 0xFFFFu) | ((unsigned)cc[3] << 16);
      } else {
#pragma unroll
        for (int j = 0; j < 4; ++j) pkv[b * 4 + j] = 0xFFFFFFFFu;
        colp[b * 2] = 0; colp[b * 2 + 1] = 0;
      }
    }
    __syncthreads();
    // in-block exclusive scan of cnt (chunks of 7, 256*7 >= NBINS)
    int c7[7];
    int s = 0;
#pragma unroll
    for (int k = 0; k < 7; ++k) {
      int i = tid * 7 + k;
      int c = (i < NBINS) ? cnt[i] : 0;
      c7[k] = c; s += c;
    }
    parts[tid] = s;
    __syncthreads();
    for (int off = 1; off < 256; off <<= 1) {     // Hillis-Steele inclusive
      int v = (tid >= off) ? parts[tid - off] : 0;
      __syncthreads();
      parts[tid] += v;
      __syncthreads();
    }
    int run = (tid > 0) ? parts[tid - 1] : 0;
#pragma unroll
    for (int k = 0; k < 7; ++k) {
      int i = tid * 7 + k;
      if (i < NBINS) {
        obot[i * BINB + bid] = (ushort)run;       // transposed offset table
        cnt[i] = run;                             // cnt becomes offset
        run += c7[k];
      }
    }
    if (tid == 0) obot[NBINS * BINB + bid] = (ushort)EPB;
    __syncthreads();
    // pass 2: pure register -> LDS placement (no global reloads)
#pragma unroll
    for (int k = 0; k < 12; ++k) {
      unsigned p = pkv[k];
      if (p != 0xFFFFFFFFu) {
        int bi = (int)(p >> 13);
        int lr5 = (int)((p >> 8) & 31u);
        int rk = (int)(p & 255u);
        unsigned cw = (colp[k >> 1] >> ((k & 1) * 16)) & 0xFFFFu;
        recbuf[cnt[bi] + rk] = ((unsigned)lr5 << 16) | cw;
      }
    }
    __syncthreads();
    // coalesced dump: 625 uint4
    uint4* gb4 = (uint4*)(binRec + base);
    const uint4* rb4 = (const uint4*)recbuf;
    for (int j = tid; j < EPB / 4; j += 256) gb4[j] = rb4[j];
  } else if (bid < BINB + 3125) {
    int i = (bid - BINB) * 256 + tid;             // 800000 threads exactly
    f32x4 a = __builtin_nontemporal_load(x4 + i * 2);        // read-once
    f32x4 b = __builtin_nontemporal_load(x4 + i * 2 + 1);
    uint4 o;
    o.x = pack2(a[0], a[1]); o.y = pack2(a[2], a[3]);
    o.z = pack2(b[0], b[1]); o.w = pack2(b[2], b[3]);
    xb4[i] = o;                                   // keep cached for fused
  } else {
    for (int i = tid; i < 2048; i += 256) {
      float4 c = W4[i * 2], d = W4[i * 2 + 1];
      uint4 w;
      w.x = pack2(c.x, c.y); w.y = pack2(c.z, c.w);
      w.z = pack2(d.x, d.y); w.w = pack2(d.z, d.w);
      Wb4[i] = w;
    }
    if (tid < 16) xb4[ZID * 16 + tid] = make_uint4(0, 0, 0, 0);  // zero row
  }
}

// Fused Stage A (256 dense runs + pad-to-8 with ZID) + Stage B (gather+
// normalize+residual, PURE 8-wide chunks -> sustained 8-deep MLP; pad loads
// hit the L1-resident zero row) + GEMM (swapped-operand MFMA, hT
// XOR-swizzled, 8 waves x 2 n-tiles). 512 threads per 32-row tile.
__global__ __launch_bounds__(512) void fused(const uint4* __restrict__ xb4,
                                             const unsigned* __restrict__ binRec,
                                             const ushort* __restrict__ obot,
                                             const uint4* __restrict__ Wb4,
                                             const float4* __restrict__ bias4,
                                             float4* __restrict__ out4) {
  __shared__ ushort hT[32 * CH];                   // 8192 B, slot s at s^(r&15)
  __shared__ __align__(16) ushort colL[32 * CAPR]; // 3072 B
  __shared__ int rowcnt[32];
  int tid = threadIdx.x;
  int g = blockIdx.x;
  int m0 = g * 32;

  // ---- Stage A: 256 dense runs, 2 threads per run; offsets coalesced ----
  if (tid < 32) rowcnt[tid] = 0;
  __syncthreads();
  {
    int i = tid >> 1, sub = tid & 1;
    int o0 = obot[g * BINB + i];                   // contiguous 512-B row
    int o1 = obot[(g + 1) * BINB + i];             // contiguous 512-B row
    const unsigned* rbase = binRec + i * EPB;
    for (int p = o0 + sub; p < o1; p += 2) {
      unsigned rec = rbase[p];
      int lr = (int)(rec >> 16);
      int pp = atomicAdd(&rowcnt[lr], 1);
      if (pp < CAPR) colL[lr * CAPR + pp] = (ushort)(rec & 0xFFFFu);
    }
  }
  __syncthreads();
  // pad each row's list to a multiple of 8 with ZID (zero-row gathers add 0)
  if (tid < 256) {
    int r = tid >> 3, k = tid & 7;
    int dc = rowcnt[r]; if (dc > CAPR) dc = CAPR;
    int pc = (dc + 7) & ~7; if (pc > CAPR) pc = CAPR;
    if (dc + k < pc) colL[r * CAPR + dc + k] = (ushort)ZID;
  }
  __syncthreads();

  // ---- Stage B: gather + normalize + residual -> hT (bf16), pure 8-wide ----
  int wv = tid >> 6;          // 0..7
  int lane = tid & 63;
  int q = lane & 15;          // uint4 chunk within a 128-ch bf16 row
  int grp = lane >> 4;        // 0..3
  int r = wv * 4 + grp;       // 0..31
  int node = m0 + r;
  int deg = rowcnt[r];
  int degc = deg < CAPR ? deg : CAPR;
  int padc = (degc + 7) & ~7; if (padc > CAPR) padc = CAPR;
  const ushort* arow = colL + r * CAPR;
  int nc = node < N_NODES ? node : 0;
  uint4 xi = xb4[nc * 16 + q];           // residual, issued before the loop
  float acc[8] = {0.f, 0.f, 0.f, 0.f, 0.f, 0.f, 0.f, 0.f};
  for (int e = 0; e < padc; e += 8) {    // 8 independent loads, no tail
    uint4 ids = *(const uint4*)(arow + e);
    int n0 = ids.x & 0xFFFF, n1 = ids.x >> 16;
    int n2 = ids.y & 0xFFFF, n3 = ids.y >> 16;
    int n4 = ids.z & 0xFFFF, n5 = ids.z >> 16;
    int n6 = ids.w & 0xFFFF, n7 = ids.w >> 16;
    uint4 v0 = xb4[n0 * 16 + q];
    uint4 v1 = xb4[n1 * 16 + q];
    uint4 v2 = xb4[n2 * 16 + q];
    uint4 v3 = xb4[n3 * 16 + q];
    uint4 v4 = xb4[n4 * 16 + q];
    uint4 v5 = xb4[n5 * 16 + q];
    uint4 v6 = xb4[n6 * 16 + q];
    uint4 v7 = xb4[n7 * 16 + q];
    addrow(acc, v0); addrow(acc, v1); addrow(acc, v2); addrow(acc, v3);
    addrow(acc, v4); addrow(acc, v5); addrow(acc, v6); addrow(acc, v7);
  }
  uint4 o = make_uint4(0, 0, 0, 0);
  if (node < N_NODES) {
    float s = 1.0f / fmaxf((float)deg, 1.0f);
    o.x = pack2(bflo(xi.x) + acc[0] * s, bfhi(xi.x) + acc[1] * s);
    o.y = pack2(bflo(xi.y) + acc[2] * s, bfhi(xi.y) + acc[3] * s);
    o.z = pack2(bflo(xi.z) + acc[4] * s, bfhi(xi.z) + acc[5] * s);
    o.w = pack2(bflo(xi.w) + acc[6] * s, bfhi(xi.w) + acc[7] * s);
  }
  *(uint4*)&hT[r * CH + ((q ^ (r & 15)) << 3)] = o;
  __syncthreads();

  // ---- GEMM: swapped-operand MFMA (proven mapping), 8 waves x 2 n-tiles.
  // hT uint4-slot s of row r lives at s^(r&15): conflict-free fragment reads.
  int qq = grp;
  int mt = wv & 1;
  int nbase = (wv >> 1) * 2;
  const ushort* hbase = &hT[(mt * 16 + q) * CH];   // row rr_: rr_&15 == q
  bf16x8 hb0 = *(const bf16x8*)(hbase + (((qq + 0) ^ q) << 3));
  bf16x8 hb1 = *(const bf16x8*)(hbase + (((qq + 4) ^ q) << 3));
  bf16x8 hb2 = *(const bf16x8*)(hbase + (((qq + 8) ^ q) << 3));
  bf16x8 hb3 = *(const bf16x8*)(hbase + (((qq + 12) ^ q) << 3));
  int m = m0 + mt * 16 + q;
#pragma unroll
  for (int i = 0; i < 2; ++i) {
    int nt = nbase + i;
    const uint4* wr = Wb4 + (nt * 16 + q) * 16 + qq;   // k-step 32 bf16 = 4 uint4
    bf16x8 w0 = __builtin_bit_cast(bf16x8, wr[0]);
    bf16x8 w1 = __builtin_bit_cast(bf16x8, wr[4]);
    bf16x8 w2 = __builtin_bit_cast(bf16x8, wr[8]);
    bf16x8 w3 = __builtin_bit_cast(bf16x8, wr[12]);
    f32x4 acc2 = {0.f, 0.f, 0.f, 0.f};
    acc2 = __builtin_amdgcn_mfma_f32_16x16x32_bf16(w0, hb0, acc2, 0, 0, 0);
    acc2 = __builtin_amdgcn_mfma_f32_16x16x32_bf16(w1, hb1, acc2, 0, 0, 0);
    acc2 = __builtin_amdgcn_mfma_f32_16x16x32_bf16(w2, hb2, acc2, 0, 0, 0);
    acc2 = __builtin_amdgcn_mfma_f32_16x16x32_bf16(w3, hb3, acc2, 0, 0, 0);
    if (m < N_NODES) {
      float4 bv = bias4[nt * 4 + qq];
      f32x4 ov;
      ov.x = acc2[0] + bv.x;
      ov.y = acc2[1] + bv.y;
      ov.z = acc2[2] + bv.z;
      ov.w = acc2[3] + bv.w;
      __builtin_nontemporal_store(ov, (f32x4*)(out4 + (size_t)m * 32 + nt * 4 + qq));
    }
  }
}

extern "C" void kernel_launch(void* const* d_in, const int* in_sizes, int n_in,
                              void* d_out, int out_size, void* d_ws, size_t ws_size,
                              hipStream_t stream) {
  const float* x  = (const float*)d_in[0];
  const int*   ei = (const int*)d_in[1];    // [2, N_EDGES]: row then col
  const float* W  = (const float*)d_in[2];
  const float* bb = (const float*)d_in[3];

  char* ws = (char*)d_ws;
  unsigned* binRec = (unsigned*)ws;
  ushort*   obot   = (ushort*)(ws + 2560000);
  uint4*    Wb4    = (uint4*)(ws + 3360768);
  uint4*    xb4    = (uint4*)(ws + 3393536);

  prep<<<BINB + 3125 + 1, 256, 0, stream>>>(ei, ei + N_EDGES, binRec, obot,
                                            (const f32x4*)x, xb4,
                                            (const float4*)W, Wb4);
  fused<<<NTILES, 512, 0, stream>>>(xb4, binRec, obot, Wb4,
                                    (const float4*)bb, (float4*)d_out);
}